// Round 8
// baseline (1127.351 us; speedup 1.0000x reference)
//
#include <hip/hip_runtime.h>
#include <cstdint>
#include <cstddef>

#define D_MODEL 1024
#define D_STATE 16
#define E_DIM   2048
#define SEQ     4096
#define M_ROWS  16384

typedef unsigned short u16;
typedef unsigned int   u32;
typedef __attribute__((ext_vector_type(8))) short short8;   // 8 bf16 = 4 VGPRs
typedef __attribute__((ext_vector_type(4))) float f32x4;

__device__ __forceinline__ u16 f2bf(float f) {
    u32 u = __float_as_uint(f);
    u32 r = (u + 0x7fffu + ((u >> 16) & 1u)) >> 16;   // RNE
    return (u16)r;
}
__device__ __forceinline__ float bf2f(u16 h) {
    return __uint_as_float(((u32)h) << 16);
}

// ---------------------------------------------------------------------------
// PACKED TILE LAYOUT: every GEMM operand is stored as fragment-linear 128x64
// bf16 tiles (8192 u16). Chunk c (0..1023, 16 B each): msub=c>>7,
// step=(c>>6)&1, ell=c&63 -> row = msub*16+(ell&15),
// cols = (step*4 + (ell>>4))*8 .. +7.  A lane's MFMA fragment (sub, step) is
// the 16 contiguous bytes at tile_base + ((sub*2+step)*64 + lane)*8 u16 --
// so fragments are loaded DIRECTLY global->VGPR, fully coalesced (the wave
// reads a contiguous 1 KB per global_load_dwordx4).
// Tile (Mt, Kt) of an [M, K] operand lives at ((Mt*(K/64) + Kt) * 8192).
// ---------------------------------------------------------------------------
#define BM 128
#define BN 128
#define HC_STR 17   // padded float stride for epilogue H/C tiles

// packed elementwise offset for XCp (K-dim = E_DIM = 2048, 32 k-tiles)
__device__ __forceinline__ size_t xcp_off(int m, int n) {
    int Mt = m >> 7, mr = m & 127;
    int Kt = n >> 6, nt = n & 63;
    int c16 = nt >> 3;
    int c = (mr >> 4) * 128 + (c16 >> 2) * 64 + (c16 & 3) * 16 + (mr & 15);
    return ((size_t)Mt * 32 + Kt) * 8192 + (size_t)c * 8 + (nt & 7);
}

// ---------------------------------------------------------------------------
// MFMA GEMM on packed operands. C[M,N] = A[M,K] @ B[N,K]^T.
// 128x128 tile, BK=64, 4 waves (2x2 of 64x64), 4x4 16x16x32 MFMA per wave.
//
// R8: DEPTH-4 REGISTER PIPELINE. R5/R7 A/B: depth-2@176VGPR = 308us beats
// depth-1@168VGPR = 333us, occupancy PINNED at 11.5% (~1 wave/SIMD) in both
// -- so VGPR shaving buys nothing (cap is elsewhere) and per-wave MLP is the
// only live lever. Inverse conclusion: at 1 wave/SIMD the full 512-VGPR file
// is free. Spend it: 8 fragment groups = 4 k-tiles in flight (256 frag VGPR
// + 64 acc ~= 350 total, launch_bounds(256,1) licenses the allocator).
// Consume->refill distance = 8 half-steps ~= 1100 cy, covering ~900 cy
// HBM-miss latency (depth-2 covered only ~250 cy). All indices static.
//
// XCD swizzle: L%8 ~ XCD; XCD x owns m-strip, sweeps n within it.
// MODE 0: out bf16 row-major = acc + bias   (-> XP)
// MODE 1: gate: XCp <- sigmoid(acc+bias) * (H@C^T + Dp*XCp), packed in-place
// MODE 2: out fp32 row-major = acc + bias   (-> final out)
// ---------------------------------------------------------------------------
template <int MODE>
__global__ __launch_bounds__(256, 1)
void mfma_gemm(const u16* __restrict__ Ag, const u16* __restrict__ Bg,
               int K, int Nst,
               const float* __restrict__ bias,
               u16* __restrict__ outb, float* __restrict__ outf,
               const float* __restrict__ Hm, const float* __restrict__ Cm,
               const float* __restrict__ Dp, u16* __restrict__ XCp)
{
    const int t     = threadIdx.x;
    const int lane  = t & 63;
    const int w     = t >> 6;
    const int col_l = lane & 15;
    const int quad  = lane >> 4;
    const int wm = (w & 1) * 64;
    const int wn = (w >> 1) * 64;

    // XCD-aware swizzle (block->XCD ~ L%8): XCD owns contiguous m-strip.
    const int L = blockIdx.y * gridDim.x + blockIdx.x;
    const int xcd = L & 7, g = L >> 3;
    const int ntile = g % gridDim.x;
    const int mtile = xcd * (gridDim.y >> 3) + g / gridDim.x;
    const int bm = mtile * BM;
    const int bn = ntile * BN;

    const int KT = K >> 6;
    // per-wave fragment base: frag (i, step) of k-tile kt lives at
    //   base + kt*8192 + (i*2+step)*512   (u16 units; 16 B per lane)
    const u16* aw = Ag + (size_t)mtile * KT * 8192 + (size_t)(w & 1) * 4096
                       + (size_t)lane * 8;
    const u16* bw = Bg + (size_t)ntile * KT * 8192 + (size_t)(w >> 1) * 4096
                       + (size_t)lane * 8;

    f32x4 acc[4][4] = {};

    // load the 8 fragments (4 A + 4 B) of one K=32 step into registers
    auto ldfrag = [&](short8* da, short8* db, size_t off, int step) {
#pragma unroll
        for (int i = 0; i < 4; ++i) {
            da[i] = *(const short8*)(aw + off + (size_t)((i * 2 + step) * 512));
            db[i] = *(const short8*)(bw + off + (size_t)((i * 2 + step) * 512));
        }
    };
    auto mfma16 = [&](short8* af, short8* bfr) {
#pragma unroll
        for (int i = 0; i < 4; ++i)
#pragma unroll
            for (int j = 0; j < 4; ++j)
                acc[i][j] = __builtin_amdgcn_mfma_f32_16x16x32_bf16(
                    af[i], bfr[j], acc[i][j], 0, 0, 0);
    };

    // depth-4 ping-pong: group g (0..7) holds k-tile (ktbase + g/2), step g&1.
    // Each group consumed then immediately refilled from 4 k-tiles ahead.
    // KT is 16 or 32 here -> always a multiple of 4.
    short8 A0[4], B0[4], A1[4], B1[4], A2[4], B2[4], A3[4], B3[4];
    short8 A4[4], B4[4], A5[4], B5[4], A6[4], B6[4], A7[4], B7[4];
    ldfrag(A0, B0, 0 * 8192, 0); ldfrag(A1, B1, 0 * 8192, 1);
    ldfrag(A2, B2, 1 * 8192, 0); ldfrag(A3, B3, 1 * 8192, 1);
    ldfrag(A4, B4, 2 * 8192, 0); ldfrag(A5, B5, 2 * 8192, 1);
    ldfrag(A6, B6, 3 * 8192, 0); ldfrag(A7, B7, 3 * 8192, 1);

    size_t off = 0;
    for (int kt = 0; kt < KT; kt += 4) {
        const bool p = (kt + 4) < KT;   // KT%4==0 -> kt+4..kt+7 all valid
        mfma16(A0, B0); if (p) ldfrag(A0, B0, off + 4 * 8192, 0);
        mfma16(A1, B1); if (p) ldfrag(A1, B1, off + 4 * 8192, 1);
        mfma16(A2, B2); if (p) ldfrag(A2, B2, off + 5 * 8192, 0);
        mfma16(A3, B3); if (p) ldfrag(A3, B3, off + 5 * 8192, 1);
        mfma16(A4, B4); if (p) ldfrag(A4, B4, off + 6 * 8192, 0);
        mfma16(A5, B5); if (p) ldfrag(A5, B5, off + 6 * 8192, 1);
        mfma16(A6, B6); if (p) ldfrag(A6, B6, off + 7 * 8192, 0);
        mfma16(A7, B7); if (p) ldfrag(A7, B7, off + 7 * 8192, 1);
        off += 4 * 8192;
    }

    // C/D layout: col = lane&15, row = quad*4 + reg   [verified m89/m91]
    if (MODE == 0) {
#pragma unroll
        for (int j = 0; j < 4; ++j) {
            int n = bn + wn + j * 16 + col_l;
            float bv = bias[n];
#pragma unroll
            for (int i = 0; i < 4; ++i) {
                int mb = bm + wm + i * 16 + quad * 4;
#pragma unroll
                for (int p = 0; p < 4; ++p)
                    outb[(size_t)(mb + p) * Nst + n] = f2bf(acc[i][j][p] + bv);
            }
        }
    } else if (MODE == 1) {
        __shared__ float Hs[BM * HC_STR];
        __shared__ float Cs[BN * HC_STR];
        for (int idx = t; idx < BM * D_STATE; idx += 256)
            Hs[(idx >> 4) * HC_STR + (idx & 15)] =
                Hm[(size_t)(bm + (idx >> 4)) * D_STATE + (idx & 15)];
        for (int idx = t; idx < BN * D_STATE; idx += 256)
            Cs[(idx >> 4) * HC_STR + (idx & 15)] =
                Cm[(size_t)(bn + (idx >> 4)) * D_STATE + (idx & 15)];
        __syncthreads();
#pragma unroll
        for (int i = 0; i < 4; ++i) {
            int ml = wm + i * 16 + quad * 4;
#pragma unroll
            for (int p = 0; p < 4; ++p) {
                float hrow[D_STATE];
#pragma unroll
                for (int s = 0; s < D_STATE; ++s)
                    hrow[s] = Hs[(ml + p) * HC_STR + s];
#pragma unroll
                for (int j = 0; j < 4; ++j) {
                    int nl = wn + j * 16 + col_l;
                    int n = bn + nl;
                    float z = acc[i][j][p] + bias[n];
                    float sig = 1.f / (1.f + __expf(-z));
                    float dot = 0.f;
#pragma unroll
                    for (int s = 0; s < D_STATE; ++s)
                        dot += hrow[s] * Cs[nl * HC_STR + s];
                    // packed in-place RMW: read & write the SAME address
                    size_t offx = xcp_off(bm + ml + p, n);
                    float xc = bf2f(XCp[offx]);
                    XCp[offx] = f2bf(sig * (dot + Dp[n] * xc));
                }
            }
        }
    } else {
#pragma unroll
        for (int j = 0; j < 4; ++j) {
            int n = bn + wn + j * 16 + col_l;
            float bv = bias[n];
#pragma unroll
            for (int i = 0; i < 4; ++i) {
                int mb = bm + wm + i * 16 + quad * 4;
#pragma unroll
                for (int p = 0; p < 4; ++p)
                    outf[(size_t)(mb + p) * Nst + n] = acc[i][j][p] + bv;
            }
        }
    }
}

// ---------------------------------------------------------------------------
// pack x fp32 [16384,1024] -> packed bf16 tiles (K-dim 1024, 16 k-tiles)
// ---------------------------------------------------------------------------
__global__ __launch_bounds__(256)
void pack_x_kernel(const float* __restrict__ x, u16* __restrict__ xp)
{
    const int Kt = blockIdx.x;   // 0..15
    const int Mt = blockIdx.y;   // 0..127
    const int t  = threadIdx.x;
    u16* dst = xp + ((size_t)Mt * 16 + Kt) * 8192;
#pragma unroll
    for (int i = 0; i < 4; ++i) {
        int c   = i * 256 + t;
        int ell = c & 63;
        int row = Mt * 128 + (c >> 7) * 16 + (ell & 15);
        int col = Kt * 64 + (((c >> 6) & 1) * 4 + (ell >> 4)) * 8;
        const float4* src = (const float4*)&x[(size_t)row * D_MODEL + col];
        float4 a = src[0], b = src[1];
        alignas(16) u16 o[8] = {f2bf(a.x), f2bf(a.y), f2bf(a.z), f2bf(a.w),
                                f2bf(b.x), f2bf(b.y), f2bf(b.z), f2bf(b.w)};
        *(short8*)(dst + c * 8) = *(const short8*)o;
    }
}

// ---------------------------------------------------------------------------
// pack W^T: src W [K, Wstride] fp32 (cols colOff..colOff+Nt*128) -> packed
// bf16 tiles of B = W^T [N, K].
// ---------------------------------------------------------------------------
__global__ __launch_bounds__(256)
void pack_w_kernel(const float* __restrict__ W, u16* __restrict__ out,
                   int Wstride, int colOff, int KT)
{
    const int Kt = blockIdx.x;
    const int Nt = blockIdx.y;
    const int t  = threadIdx.x;
    u16* dst = out + ((size_t)Nt * KT + Kt) * 8192;
#pragma unroll
    for (int i = 0; i < 4; ++i) {
        int c    = i * 256 + t;
        int ell  = c & 63;
        int nrow = Nt * 128 + (c >> 7) * 16 + (ell & 15);
        int kcol = Kt * 64 + (((c >> 6) & 1) * 4 + (ell >> 4)) * 8;
        alignas(16) u16 o[8];
#pragma unroll
        for (int q = 0; q < 8; ++q)
            o[q] = f2bf(W[(size_t)(kcol + q) * Wstride + colOff + nrow]);
        *(short8*)(dst + c * 8) = *(const short8*)o;
    }
}

// ---------------------------------------------------------------------------
// causal depthwise conv (taps=4): XP row-major bf16 -> XCp PACKED bf16.
// block per (k-tile, m-tile); writes are fully linear per tile.
// ---------------------------------------------------------------------------
__global__ __launch_bounds__(256)
void conv_kernel(const u16* __restrict__ XP, const float* __restrict__ conv_w,
                 const float* __restrict__ conv_b, u16* __restrict__ XCp)
{
    const int Kt = blockIdx.x;   // 0..31
    const int Mt = blockIdx.y;   // 0..127
    const int t  = threadIdx.x;
    u16* dst = XCp + ((size_t)Mt * 32 + Kt) * 8192;
#pragma unroll
    for (int i = 0; i < 4; ++i) {
        int c   = i * 256 + t;
        int ell = c & 63;
        int mr  = (c >> 7) * 16 + (ell & 15);
        int e   = Kt * 64 + (((c >> 6) & 1) * 4 + (ell >> 4)) * 8;
        int m   = Mt * 128 + mr;
        int l   = m & (SEQ - 1);
        float acc[8];
        {
            float4 c0 = *(const float4*)&conv_b[e];
            float4 c1 = *(const float4*)&conv_b[e + 4];
            acc[0] = c0.x; acc[1] = c0.y; acc[2] = c0.z; acc[3] = c0.w;
            acc[4] = c1.x; acc[5] = c1.y; acc[6] = c1.z; acc[7] = c1.w;
        }
#pragma unroll
        for (int k = 0; k < 4; ++k) {
            if (l - 3 + k >= 0) {
                const short8 xv = *(const short8*)&XP[(size_t)(m - 3 + k) * E_DIM + e];
#pragma unroll
                for (int j = 0; j < 8; ++j)
                    acc[j] += bf2f((u16)xv[j]) * conv_w[(size_t)(e + j) * 4 + k];
            }
        }
        alignas(16) u16 o[8];
#pragma unroll
        for (int j = 0; j < 8; ++j) o[j] = f2bf(acc[j]);
        *(short8*)(dst + c * 8) = *(const short8*)o;
    }
}

// ---------------------------------------------------------------------------
// R5: U partials. block per (Kt-pair kp, Mt); thread t owns row rr=t>>1,
// col-half z=t&1, reads the 8 CONTIGUOUS chunks of its row in each packed
// tile (wave = 4x256 B contiguous segments per q-step -> full line
// utilization). Pair-reduce via one shfl_xor(1); partials Up[kp][m][s]
// summed by u_reduce_kernel. Deterministic; no LDS.
// chunk c for (rr, z, q): c = (rr>>4)*128 + z*64 + q*16 + (rr&15)
//   -> row = rr, cols = (z*4+q)*8 .. +7   [packed-layout identities]
// ---------------------------------------------------------------------------
__global__ __launch_bounds__(256)
void u_part_kernel(const u16* __restrict__ XCp, const float* __restrict__ Amat,
                   float* __restrict__ Up)
{
    const int kp = blockIdx.x;   // 0..15 (K-tile pair)
    const int Mt = blockIdx.y;   // 0..127
    const int t  = threadIdx.x;
    const int rr = t >> 1;       // row within tile, 0..127
    const int z  = t & 1;        // col-half (step)
    const int msub = rr >> 4, r = rr & 15;

    float acc[16];
#pragma unroll
    for (int s = 0; s < 16; ++s) acc[s] = 0.f;

#pragma unroll
    for (int kk = 0; kk < 2; ++kk) {
        const int Kt = kp * 2 + kk;
        const u16* tile = XCp + ((size_t)Mt * 32 + Kt) * 8192;
#pragma unroll
        for (int q = 0; q < 4; ++q) {
            const int c = msub * 128 + z * 64 + q * 16 + r;
            const short8 xv = *(const short8*)(tile + (size_t)c * 8);
            const int e0 = Kt * 64 + (z * 4 + q) * 8;
#pragma unroll
            for (int j = 0; j < 8; ++j) {
                float xq = bf2f((u16)xv[j]);
                const float4* ar = (const float4*)&Amat[(size_t)(e0 + j) * D_STATE];
#pragma unroll
                for (int s4 = 0; s4 < 4; ++s4) {
                    float4 a = ar[s4];
                    acc[s4 * 4 + 0] += xq * a.x; acc[s4 * 4 + 1] += xq * a.y;
                    acc[s4 * 4 + 2] += xq * a.z; acc[s4 * 4 + 3] += xq * a.w;
                }
            }
        }
    }
    // combine the two col-halves (partner lane = t^1, same row)
#pragma unroll
    for (int s = 0; s < 16; ++s) acc[s] += __shfl_xor(acc[s], 1);

    if (z == 0) {
        const int m = Mt * 128 + rr;
        float4* dst = (float4*)&Up[((size_t)kp * M_ROWS + m) * D_STATE];
        dst[0] = make_float4(acc[0], acc[1], acc[2], acc[3]);
        dst[1] = make_float4(acc[4], acc[5], acc[6], acc[7]);
        dst[2] = make_float4(acc[8], acc[9], acc[10], acc[11]);
        dst[3] = make_float4(acc[12], acc[13], acc[14], acc[15]);
    }
}

// U[m,s] = sum_kp Up[kp][m][s]   (16 coalesced slices, float4-vectorized)
__global__ __launch_bounds__(256)
void u_reduce_kernel(const float* __restrict__ Up, float* __restrict__ U)
{
    const int idx = blockIdx.x * 256 + threadIdx.x;   // 65536 float4 elems
    const float4* src = (const float4*)Up;
    float4 s = src[idx];
#pragma unroll
    for (int kp = 1; kp < 16; ++kp) {
        float4 v = src[(size_t)kp * (M_ROWS * D_STATE / 4) + idx];
        s.x += v.x; s.y += v.y; s.z += v.z; s.w += v.w;
    }
    ((float4*)U)[idx] = s;
}

// ---------------------------------------------------------------------------
// sequential scan: h_l = tanh(U_l + h_{l-1}), 64 chains.
// Chunked by 8 with FULLY-UNROLLED static-index arrays (stay in VGPRs).
// Next chunk's 8 independent loads issue before this chunk's ~290-cycle
// dependent tanh chain, covering L2/L3 latency.
// ---------------------------------------------------------------------------
__global__ __launch_bounds__(64)
void scan_kernel(const float* __restrict__ U, float* __restrict__ H)
{
    const int t = threadIdx.x;
    const int b = t >> 4;
    const int s = t & 15;
    const float* u = U + (size_t)b * SEQ * D_STATE + s;
    float*       h = H + (size_t)b * SEQ * D_STATE + s;

    float cur[8], nxt[8];
#pragma unroll
    for (int j = 0; j < 8; ++j) cur[j] = u[(size_t)j * D_STATE];

    float hv = 0.f;
    for (int l0 = 0; l0 < SEQ; l0 += 8) {
        if (l0 + 8 < SEQ) {
#pragma unroll
            for (int j = 0; j < 8; ++j)
                nxt[j] = u[(size_t)(l0 + 8 + j) * D_STATE];
        }
#pragma unroll
        for (int j = 0; j < 8; ++j) {
            float ex = __expf(2.f * (cur[j] + hv));
            hv = 1.f - 2.f / (ex + 1.f);
            h[(size_t)(l0 + j) * D_STATE] = hv;
        }
#pragma unroll
        for (int j = 0; j < 8; ++j) cur[j] = nxt[j];
    }
}

// ---------------------------------------------------------------------------
extern "C" void kernel_launch(void* const* d_in, const int* in_sizes, int n_in,
                              void* d_out, int out_size, void* d_ws, size_t ws_size,
                              hipStream_t stream)
{
    const float* x      = (const float*)d_in[0];
    const float* W_in   = (const float*)d_in[1];
    const float* b_in   = (const float*)d_in[2];
    const float* conv_w = (const float*)d_in[3];
    const float* conv_b = (const float*)d_in[4];
    const float* Amat   = (const float*)d_in[5];
    const float* Cmat   = (const float*)d_in[6];
    const float* Dp     = (const float*)d_in[7];
    const float* W_out  = (const float*)d_in[8];
    const float* b_out  = (const float*)d_in[9];
    float* out = (float*)d_out;

    // workspace layout (132.1 MB total; 136 MB proven safe)
    char* ws = (char*)d_ws;
    u16*   xbp  = (u16*)(ws);                    // 33.55 MB packed x
    u16*   Wp0  = (u16*)(ws +  33554432);        //  4.19 MB packed W_in[:, :2048]^T
    u16*   Wp1  = (u16*)(ws +  37748736);        //  4.19 MB packed W_in[:, 2048:]^T
    u16*   Wp2  = (u16*)(ws +  41943040);        //  4.19 MB packed W_out^T
    u16*   XCp  = (u16*)(ws +  46137344);        // 67.11 MB packed x_conv
    float* U    = (float*)(ws + 113246208);      //  1.05 MB
    float* H    = (float*)(ws + 114294784);      //  1.05 MB
    float* Up   = (float*)(ws + 115343360);      // 16.78 MB U partials (16x)
    u16*   XP   = (u16*)d_out;  // x_proj bf16 in d_out (67.1 MB), dead after conv

    // 1) pack inputs
    pack_x_kernel<<<dim3(16, 128), 256, 0, stream>>>(x, xbp);
    pack_w_kernel<<<dim3(16, 16), 256, 0, stream>>>(W_in, Wp0, 2 * E_DIM, 0, 16);
    pack_w_kernel<<<dim3(16, 16), 256, 0, stream>>>(W_in, Wp1, 2 * E_DIM, E_DIM, 16);
    pack_w_kernel<<<dim3(32, 8), 256, 0, stream>>>(W_out, Wp2, D_MODEL, 0, 32);

    // 2) XP = bf16(x @ W_in[:, :2048] + b_in)   (row-major, -> d_out)
    mfma_gemm<0><<<dim3(16, 128), 256, 0, stream>>>(
        xbp, Wp0, D_MODEL, E_DIM, b_in, XP, nullptr, nullptr, nullptr, nullptr, nullptr);

    // 3) XCp = packed bf16(causal_conv(XP) + conv_b)
    conv_kernel<<<dim3(32, 128), 256, 0, stream>>>(XP, conv_w, conv_b, XCp);

    // 4) U = XC @ A  (partials + reduce); 5) scan -> H
    u_part_kernel<<<dim3(16, 128), 256, 0, stream>>>(XCp, Amat, Up);
    u_reduce_kernel<<<256, 256, 0, stream>>>(Up, U);
    scan_kernel<<<1, 64, 0, stream>>>(U, H);

    // 6) XCp <- sigmoid(x @ W_in[:, 2048:] + b_in[2048:]) * (H@C^T + Dp*XCp)
    mfma_gemm<1><<<dim3(16, 128), 256, 0, stream>>>(
        xbp, Wp1, D_MODEL, 0, b_in + E_DIM, nullptr, nullptr, H, Cmat, Dp, XCp);

    // 7) out = XC @ W_out + b_out   (fp32, row-major)
    mfma_gemm<2><<<dim3(8, 128), 256, 0, stream>>>(
        XCp, Wp2, E_DIM, D_MODEL, b_out, nullptr, out, nullptr, nullptr, nullptr, nullptr);
}